// Round 1
// baseline (145.758 us; speedup 1.0000x reference)
//
#include <hip/hip_runtime.h>
#include <hip/hip_bf16.h>

#define POOLSZ 7
#define FH 64
#define FW 64
#define FC 1024

// One block per (n, py, px) cell. 256 threads x float4 = 1024 channels.
// feat layout NHWC: feat[(y*FW + x)*FC + c]; out layout (N, 7,7,C) flat.
__global__ __launch_bounds__(256) void roi_pool_kernel(
    const float* __restrict__ feat,
    const float* __restrict__ rois,
    const int* __restrict__ stride_p,
    float* __restrict__ out)
{
    const int blk = blockIdx.x;          // n*49 + py*7 + px
    const int px = blk % POOLSZ;
    const int py = (blk / POOLSZ) % POOLSZ;
    const int n  = blk / (POOLSZ * POOLSZ);

    const float s = (float)(*stride_p);

    // r = (rois / stride).astype(int32)  (rois >= 0, trunc == floor)
    const float4 rv = ((const float4*)rois)[n];
    const int ymin = (int)(rv.x / s);
    const int xmin = (int)(rv.y / s);
    const int ymax = (int)(rv.z / s);
    const int xmax = (int)(rv.w / s);

    // axis_coords, y axis (match reference op order exactly)
    const float in_h = (float)(ymax - ymin + 1);
    const float sy   = in_h / (float)POOLSZ;
    const float srcy = (float)py * sy;
    const int   iy0  = (int)floorf(srcy);
    const float dy   = srcy - (float)iy0;
    const int   iy1  = min(iy0 + 1, ymax - ymin);
    const int   y0   = ymin + iy0;
    const int   y1   = ymin + iy1;

    // x axis
    const float in_w = (float)(xmax - xmin + 1);
    const float sx   = in_w / (float)POOLSZ;
    const float srcx = (float)px * sx;
    const int   ix0  = (int)floorf(srcx);
    const float dx   = srcx - (float)ix0;
    const int   ix1  = min(ix0 + 1, xmax - xmin);
    const int   x0   = xmin + ix0;
    const int   x1   = xmin + ix1;

    const int c4 = threadIdx.x;          // 0..255, one float4 each
    const float4* __restrict__ f4 = (const float4*)feat;
    const int C4 = FC / 4;

    const float4 f00 = f4[(y0 * FW + x0) * C4 + c4];
    const float4 f01 = f4[(y0 * FW + x1) * C4 + c4];
    const float4 f10 = f4[(y1 * FW + x0) * C4 + c4];
    const float4 f11 = f4[(y1 * FW + x1) * C4 + c4];

    float4 o;
    {
        float top, bot;
        top = f00.x + (f01.x - f00.x) * dx;
        bot = f10.x + (f11.x - f10.x) * dx;
        o.x = top + (bot - top) * dy;
        top = f00.y + (f01.y - f00.y) * dx;
        bot = f10.y + (f11.y - f10.y) * dx;
        o.y = top + (bot - top) * dy;
        top = f00.z + (f01.z - f00.z) * dx;
        bot = f10.z + (f11.z - f10.z) * dx;
        o.z = top + (bot - top) * dy;
        top = f00.w + (f01.w - f00.w) * dx;
        bot = f10.w + (f11.w - f10.w) * dx;
        o.w = top + (bot - top) * dy;
    }

    ((float4*)out)[blk * C4 + c4] = o;
}

extern "C" void kernel_launch(void* const* d_in, const int* in_sizes, int n_in,
                              void* d_out, int out_size, void* d_ws, size_t ws_size,
                              hipStream_t stream) {
    const float* feat   = (const float*)d_in[0];   // (1,64,64,1024) f32
    const float* rois   = (const float*)d_in[1];   // (N,4) f32
    const int*   stride = (const int*)d_in[2];     // scalar int
    float* out = (float*)d_out;

    const int N = in_sizes[1] / 4;                 // 512
    const int blocks = N * POOLSZ * POOLSZ;        // 25088

    roi_pool_kernel<<<blocks, 256, 0, stream>>>(feat, rois, stride, out);
}

// Round 2
// 144.897 us; speedup vs baseline: 1.0059x; 1.0059x over previous
//
#include <hip/hip_runtime.h>
#include <hip/hip_bf16.h>

#define POOLSZ 7
#define FW 64
#define FC 1024
#define C4 (FC / 4)

typedef float v4f __attribute__((ext_vector_type(4)));

struct Cell {
    int p00, p01, p10, p11;   // pixel index (y*FW + x)
    float dx, dy;
};

__device__ __forceinline__ Cell cell_addr(const v4f rv, float s, int py, int px)
{
    // r = (rois / stride).astype(int32); rois >= 0 so trunc == floor
    const int ymin = (int)(rv.x / s);
    const int xmin = (int)(rv.y / s);
    const int ymax = (int)(rv.z / s);
    const int xmax = (int)(rv.w / s);

    // match reference op order exactly: scale = in_size/POOL, src = j*scale
    const float sy   = (float)(ymax - ymin + 1) / (float)POOLSZ;
    const float srcy = (float)py * sy;
    const int   iy0  = (int)floorf(srcy);
    const float dy   = srcy - (float)iy0;
    const int   iy1  = min(iy0 + 1, ymax - ymin);
    const int   y0   = ymin + iy0;
    const int   y1   = ymin + iy1;

    const float sx   = (float)(xmax - xmin + 1) / (float)POOLSZ;
    const float srcx = (float)px * sx;
    const int   ix0  = (int)floorf(srcx);
    const float dx   = srcx - (float)ix0;
    const int   ix1  = min(ix0 + 1, xmax - xmin);
    const int   x0   = xmin + ix0;
    const int   x1   = xmin + ix1;

    Cell c;
    c.p00 = y0 * FW + x0;
    c.p01 = y0 * FW + x1;
    c.p10 = y1 * FW + x0;
    c.p11 = y1 * FW + x1;
    c.dx = dx;
    c.dy = dy;
    return c;
}

__device__ __forceinline__ v4f lerp2d(v4f f00, v4f f01, v4f f10, v4f f11,
                                      float dx, float dy)
{
    v4f top = f00 + (f01 - f00) * dx;
    v4f bot = f10 + (f11 - f10) * dx;
    return top + (bot - top) * dy;
}

// Two (n,py,px) cells per block; 256 threads x one float4 of the 1024 channels.
// 8 independent feat loads in flight per thread; nontemporal output stores.
__global__ __launch_bounds__(256) void roi_pool_kernel(
    const v4f* __restrict__ f4,
    const v4f* __restrict__ rois4,
    const int* __restrict__ stride_p,
    v4f* __restrict__ out4)
{
    const float s = (float)(*stride_p);
    const int c4 = threadIdx.x;

    const int cellA = blockIdx.x * 2;
    const int cellB = cellA + 1;

    const int pxA = cellA % POOLSZ;
    const int pyA = (cellA / POOLSZ) % POOLSZ;
    const int nA  = cellA / (POOLSZ * POOLSZ);
    const int pxB = cellB % POOLSZ;
    const int pyB = (cellB / POOLSZ) % POOLSZ;
    const int nB  = cellB / (POOLSZ * POOLSZ);

    const v4f rvA = rois4[nA];
    const v4f rvB = rois4[nB];
    const Cell a = cell_addr(rvA, s, pyA, pxA);
    const Cell b = cell_addr(rvB, s, pyB, pxB);

    // 8 independent loads — issue all before any use
    const v4f a00 = f4[a.p00 * C4 + c4];
    const v4f a01 = f4[a.p01 * C4 + c4];
    const v4f a10 = f4[a.p10 * C4 + c4];
    const v4f a11 = f4[a.p11 * C4 + c4];
    const v4f b00 = f4[b.p00 * C4 + c4];
    const v4f b01 = f4[b.p01 * C4 + c4];
    const v4f b10 = f4[b.p10 * C4 + c4];
    const v4f b11 = f4[b.p11 * C4 + c4];

    const v4f oA = lerp2d(a00, a01, a10, a11, a.dx, a.dy);
    const v4f oB = lerp2d(b00, b01, b10, b11, b.dx, b.dy);

    // out never re-read: bypass L2 so feat stays resident
    __builtin_nontemporal_store(oA, &out4[cellA * C4 + c4]);
    __builtin_nontemporal_store(oB, &out4[cellB * C4 + c4]);
}

extern "C" void kernel_launch(void* const* d_in, const int* in_sizes, int n_in,
                              void* d_out, int out_size, void* d_ws, size_t ws_size,
                              hipStream_t stream) {
    const v4f* feat   = (const v4f*)d_in[0];   // (1,64,64,1024) f32
    const v4f* rois   = (const v4f*)d_in[1];   // (N,4) f32
    const int* stride = (const int*)d_in[2];   // scalar int
    v4f* out = (v4f*)d_out;

    const int N = in_sizes[1] / 4;                      // 512
    const int cells = N * POOLSZ * POOLSZ;              // 25088 (even)
    const int blocks = cells / 2;                       // 12544

    roi_pool_kernel<<<blocks, 256, 0, stream>>>(feat, rois, stride, out);
}